// Round 1
// baseline (80.527 us; speedup 1.0000x reference)
//
#include <hip/hip_runtime.h>
#include <hip/hip_bf16.h>

// Problem constants (n=48, m=32, d_model=512, H=8, DK=64, d_query=256, d_time=64)
#define NQ 48
#define NM 32
#define DMODEL 512
#define HH 8
#define DK 64

typedef __bf16 bf16x8 __attribute__((ext_vector_type(8)));
typedef float f32x4 __attribute__((ext_vector_type(4)));

// ---------------------------------------------------------------------------
// Kernel A: projections q,t,k,v (f32) + Wo split into bf16 hi/lo, transposed.
//   blocks 0..319  : projection half-rows (160 rows x 2 halves), 256 thr each
//   blocks 320..383: Wo 64x64 tile split+transpose
// ---------------------------------------------------------------------------
__global__ __launch_bounds__(256) void proj_split_kernel(
    const float* __restrict__ query, const float* __restrict__ key,
    const float* __restrict__ value, const float* __restrict__ time_,
    const float* __restrict__ Wq, const float* __restrict__ bq,
    const float* __restrict__ Wt, const float* __restrict__ bt,
    const float* __restrict__ Wk, const float* __restrict__ bk,
    const float* __restrict__ Wv, const float* __restrict__ bv,
    const float* __restrict__ Wo,
    float* __restrict__ qp, float* __restrict__ tp,
    float* __restrict__ kp, float* __restrict__ vp,
    __bf16* __restrict__ woT)
{
  int b = blockIdx.x;
  int t = threadIdx.x;
  if (b < 320) {
    int row = b >> 1;
    int col = ((b & 1) << 8) | t;
    const float* in; const float* W; const float* bias; float* outp; int K;
    if (row < 48)       { in = query + row*256;        W = Wq; bias = bq; outp = qp + row*512;       K = 256; }
    else if (row < 96)  { in = time_ + (row-48)*64;    W = Wt; bias = bt; outp = tp + (row-48)*512;  K = 64;  }
    else if (row < 128) { in = key + (row-96)*512;     W = Wk; bias = bk; outp = kp + (row-96)*512;  K = 512; }
    else                { in = value + (row-128)*512;  W = Wv; bias = bv; outp = vp + (row-128)*512; K = 512; }
    float a0=0.f, a1=0.f, a2=0.f, a3=0.f;
    for (int i = 0; i < K; i += 4) {
      a0 = fmaf(in[i+0], W[(i+0)*512 + col], a0);
      a1 = fmaf(in[i+1], W[(i+1)*512 + col], a1);
      a2 = fmaf(in[i+2], W[(i+2)*512 + col], a2);
      a3 = fmaf(in[i+3], W[(i+3)*512 + col], a3);
    }
    outp[col] = (a0+a1) + (a2+a3) + bias[col];
  } else {
    // Wo split + transpose: woT[n][k] (K padded to 1024: [0..511]=hi, [512..1023]=lo)
    __shared__ float tile[64][65];
    int tb = b - 320;
    int k0 = (tb >> 3) << 6;
    int n0 = (tb & 7) << 6;
    #pragma unroll
    for (int e = 0; e < 16; ++e) {
      int idx = t + (e << 8);
      int r = idx >> 6, c = idx & 63;
      tile[r][c] = Wo[(k0 + r)*512 + n0 + c];
    }
    __syncthreads();
    #pragma unroll
    for (int e = 0; e < 16; ++e) {
      int idx = t + (e << 8);
      int nn = idx >> 6, kk = idx & 63;
      float f = tile[kk][nn];
      __bf16 hi = (__bf16)f;
      __bf16 lo = (__bf16)(f - (float)hi);
      woT[(n0+nn)*1024 + (k0+kk)]       = hi;
      woT[(n0+nn)*1024 + 512 + (k0+kk)] = lo;
    }
  }
}

// ---------------------------------------------------------------------------
// Kernel B: fused two-stage feature-axis attention.
// Grid (m=32, n=48), block 512 = 8 waves (one per head), lane = feature d.
// Writes x as split-bf16 rows [1536][1024] ( [0..511]=hi, [512..1023]=lo ).
// ---------------------------------------------------------------------------
__global__ __launch_bounds__(512) void attn_kernel(
    const float* __restrict__ qp, const float* __restrict__ tp,
    const float* __restrict__ kp, const float* __restrict__ vp,
    __bf16* __restrict__ xs)
{
  __shared__ float kl[HH][DK], vl[HH][DK], cvl[HH][DK];
  int m = blockIdx.x, n = blockIdx.y;
  int h = threadIdx.x >> 6, lane = threadIdx.x & 63;

  float kd = kp[m*512 + h*64 + lane];
  float vd = vp[m*512 + h*64 + lane];
  kl[h][lane] = kd;
  vl[h][lane] = vd;

  float kmax = kd, kmin = kd;
  #pragma unroll
  for (int off = 32; off > 0; off >>= 1) {
    kmax = fmaxf(kmax, __shfl_xor(kmax, off));
    kmin = fminf(kmin, __shfl_xor(kmin, off));
  }
  float a  = qp[n*512 + h*64 + lane] * 0.125f;
  float mx = fmaxf(a*kmax, a*kmin);
  __syncthreads();

  float d0=0.f,d1=0.f,d2=0.f,d3=0.f, s0=0.f,s1=0.f,s2=0.f,s3=0.f;
  #pragma unroll
  for (int j = 0; j < 64; j += 4) {
    float e0 = __expf(fmaf(a, kl[h][j+0], -mx));
    float e1 = __expf(fmaf(a, kl[h][j+1], -mx));
    float e2 = __expf(fmaf(a, kl[h][j+2], -mx));
    float e3 = __expf(fmaf(a, kl[h][j+3], -mx));
    d0 += e0; d1 += e1; d2 += e2; d3 += e3;
    s0 = fmaf(e0, vl[h][j+0], s0);
    s1 = fmaf(e1, vl[h][j+1], s1);
    s2 = fmaf(e2, vl[h][j+2], s2);
    s3 = fmaf(e3, vl[h][j+3], s3);
  }
  float cv = ((s0+s1)+(s2+s3)) / ((d0+d1)+(d2+d3));
  cvl[h][lane] = cv;

  float cmax = cv, cmin = cv;
  #pragma unroll
  for (int off = 32; off > 0; off >>= 1) {
    cmax = fmaxf(cmax, __shfl_xor(cmax, off));
    cmin = fminf(cmin, __shfl_xor(cmin, off));
  }
  float bt2 = tp[n*512 + h*64 + lane] * 0.125f;
  float mx2 = fmaxf(bt2*cmax, bt2*cmin);
  __syncthreads();

  d0=d1=d2=d3=0.f; s0=s1=s2=s3=0.f;
  #pragma unroll
  for (int j = 0; j < 64; j += 4) {
    float c0 = cvl[h][j+0], c1 = cvl[h][j+1], c2 = cvl[h][j+2], c3 = cvl[h][j+3];
    float e0 = __expf(fmaf(bt2, c0, -mx2));
    float e1 = __expf(fmaf(bt2, c1, -mx2));
    float e2 = __expf(fmaf(bt2, c2, -mx2));
    float e3 = __expf(fmaf(bt2, c3, -mx2));
    d0 += e0; d1 += e1; d2 += e2; d3 += e3;
    s0 = fmaf(e0, c0, s0);
    s1 = fmaf(e1, c1, s1);
    s2 = fmaf(e2, c2, s2);
    s3 = fmaf(e3, c3, s3);
  }
  float o = ((s0+s1)+(s2+s3)) / ((d0+d1)+(d2+d3));

  int row = n*32 + m;
  int c   = h*64 + lane;
  __bf16 hi = (__bf16)o;
  __bf16 lo = (__bf16)(o - (float)hi);
  xs[row*1024 + c]       = hi;
  xs[row*1024 + 512 + c] = lo;
}

// ---------------------------------------------------------------------------
// Kernel C: out = x @ Wo + bo via split-bf16 MFMA, M=1536 N=512 K=1024.
// Grid (16,48), 1 wave/block computing a 32x32 tile (2x2 of 16x16x32 MFMA).
// ---------------------------------------------------------------------------
__global__ __launch_bounds__(64) void gemm_out_kernel(
    const __bf16* __restrict__ xs, const __bf16* __restrict__ woT,
    const float* __restrict__ bo, float* __restrict__ out)
{
  int n0 = blockIdx.x << 5;
  int m0 = blockIdx.y << 5;
  int l = threadIdx.x;
  int lhi = l >> 4, llo = l & 15;

  f32x4 acc00 = {0.f,0.f,0.f,0.f};
  f32x4 acc01 = {0.f,0.f,0.f,0.f};
  f32x4 acc10 = {0.f,0.f,0.f,0.f};
  f32x4 acc11 = {0.f,0.f,0.f,0.f};

  const __bf16* pa0 = xs  + (m0 + llo)*1024      + lhi*8;
  const __bf16* pa1 = pa0 + 16*1024;
  const __bf16* pb0 = woT + (n0 + llo)*1024      + lhi*8;
  const __bf16* pb1 = pb0 + 16*1024;

  #pragma unroll 4
  for (int kc = 0; kc < 1024; kc += 32) {
    bf16x8 a0 = *(const bf16x8*)(pa0 + kc);
    bf16x8 a1 = *(const bf16x8*)(pa1 + kc);
    bf16x8 b0 = *(const bf16x8*)(pb0 + kc);
    bf16x8 b1 = *(const bf16x8*)(pb1 + kc);
    acc00 = __builtin_amdgcn_mfma_f32_16x16x32_bf16(a0, b0, acc00, 0, 0, 0);
    acc01 = __builtin_amdgcn_mfma_f32_16x16x32_bf16(a0, b1, acc01, 0, 0, 0);
    acc10 = __builtin_amdgcn_mfma_f32_16x16x32_bf16(a1, b0, acc10, 0, 0, 0);
    acc11 = __builtin_amdgcn_mfma_f32_16x16x32_bf16(a1, b1, acc11, 0, 0, 0);
  }

  int colA = n0 + llo, colB = colA + 16;
  float boA = bo[colA], boB = bo[colB];
  #pragma unroll
  for (int r = 0; r < 4; ++r) {
    int rowA = m0 + (lhi << 2) + r;
    int rowB = rowA + 16;
    out[rowA*512 + colA] = acc00[r] + boA;
    out[rowA*512 + colB] = acc01[r] + boB;
    out[rowB*512 + colA] = acc10[r] + boA;
    out[rowB*512 + colB] = acc11[r] + boB;
  }
}

// ---------------------------------------------------------------------------
extern "C" void kernel_launch(void* const* d_in, const int* in_sizes, int n_in,
                              void* d_out, int out_size, void* d_ws, size_t ws_size,
                              hipStream_t stream) {
  const float* query = (const float*)d_in[0];
  const float* key   = (const float*)d_in[1];
  const float* value = (const float*)d_in[2];
  const float* time_ = (const float*)d_in[3];
  const float* Wq = (const float*)d_in[4];
  const float* bq = (const float*)d_in[5];
  const float* Wt = (const float*)d_in[6];
  const float* bt = (const float*)d_in[7];
  const float* Wk = (const float*)d_in[8];
  const float* bk = (const float*)d_in[9];
  const float* Wv = (const float*)d_in[10];
  const float* bv = (const float*)d_in[11];
  const float* Wo = (const float*)d_in[12];
  const float* bo = (const float*)d_in[13];

  // ws layout: qp[48*512] tp[48*512] kp[32*512] vp[32*512] (f32),
  //            xs[1536*1024] woT[512*1024] (bf16)  -> total ~4.4 MB
  float* qp = (float*)d_ws;
  float* tp = qp + 48*512;
  float* kp = tp + 48*512;
  float* vp = kp + 32*512;
  __bf16* xs  = (__bf16*)(vp + 32*512);
  __bf16* woT = xs + 1536*1024;
  float* out = (float*)d_out;

  hipLaunchKernelGGL(proj_split_kernel, dim3(384), dim3(256), 0, stream,
                     query, key, value, time_, Wq, bq, Wt, bt, Wk, bk, Wv, bv, Wo,
                     qp, tp, kp, vp, woT);
  hipLaunchKernelGGL(attn_kernel, dim3(32, 48), dim3(512), 0, stream,
                     qp, tp, kp, vp, xs);
  hipLaunchKernelGGL(gemm_out_kernel, dim3(16, 48), dim3(64), 0, stream,
                     xs, woT, bo, out);
}

// Round 2
// 78.909 us; speedup vs baseline: 1.0205x; 1.0205x over previous
//
#include <hip/hip_runtime.h>
#include <hip/hip_bf16.h>

// n=48, m=32, d_model=512, H=8, DK=64, d_query=256, d_time=64
#define HH 8
#define DK 64

typedef __bf16 bf16x8 __attribute__((ext_vector_type(8)));
typedef float f32x4 __attribute__((ext_vector_type(4)));

// ---------------------------------------------------------------------------
// Kernel S: split everything to bf16 hi/lo.
//  blocks [0,232):  weight transpose+split  W[K][512] -> WT[512][2K] (hi|lo)
//  blocks [232,279): input split  X[M][K] -> XS[M][2K] (hi|lo), no transpose
// ---------------------------------------------------------------------------
__global__ __launch_bounds__(256) void split_kernel(
    const float* __restrict__ query, const float* __restrict__ key,
    const float* __restrict__ value, const float* __restrict__ time_,
    const float* __restrict__ Wq, const float* __restrict__ Wt,
    const float* __restrict__ Wk, const float* __restrict__ Wv,
    const float* __restrict__ Wo,
    __bf16* __restrict__ xq, __bf16* __restrict__ xt,
    __bf16* __restrict__ xk, __bf16* __restrict__ xv,
    __bf16* __restrict__ wTq, __bf16* __restrict__ wTt,
    __bf16* __restrict__ wTk, __bf16* __restrict__ wTv,
    __bf16* __restrict__ woT)
{
  int b = blockIdx.x, t = threadIdx.x;
  if (b < 232) {
    const float* W; __bf16* WT; int K, tb;
    if (b < 32)       { W = Wq; WT = wTq; K = 256; tb = b; }
    else if (b < 40)  { W = Wt; WT = wTt; K = 64;  tb = b - 32; }
    else if (b < 104) { W = Wk; WT = wTk; K = 512; tb = b - 40; }
    else if (b < 168) { W = Wv; WT = wTv; K = 512; tb = b - 104; }
    else              { W = Wo; WT = woT; K = 512; tb = b - 168; }
    int kt = tb >> 3, nt = tb & 7;     // ntiles = 8 always (N=512)
    int k0 = kt << 6, n0 = nt << 6;
    __shared__ float tile[64][65];
    #pragma unroll
    for (int e = 0; e < 16; ++e) {
      int idx = t + (e << 8);
      int r = idx >> 6, c = idx & 63;
      tile[r][c] = W[(k0 + r) * 512 + n0 + c];
    }
    __syncthreads();
    int K2 = K << 1;
    #pragma unroll
    for (int e = 0; e < 16; ++e) {
      int idx = t + (e << 8);
      int nn = idx >> 6, kk = idx & 63;
      float f = tile[kk][nn];
      __bf16 hi = (__bf16)f;
      __bf16 lo = (__bf16)(f - (float)hi);
      WT[(n0 + nn) * K2 + k0 + kk]     = hi;
      WT[(n0 + nn) * K2 + K + k0 + kk] = lo;
    }
  } else {
    // flat element ranges: q 12288 | t 3072 | k 16384 | v 16384  (total 48128)
    int e0 = ((b - 232) << 10) + t;
    #pragma unroll
    for (int i = 0; i < 4; ++i) {
      int e = e0 + (i << 8);
      const float* src; __bf16* dst; int row, k, K;
      if (e < 12288)      { src = query; dst = xq; row = e >> 8, k = e & 255; K = 256; }
      else if (e < 15360) { int r = e - 12288; src = time_; dst = xt; row = r >> 6, k = r & 63;  K = 64; }
      else if (e < 31744) { int r = e - 15360; src = key;   dst = xk; row = r >> 9, k = r & 511; K = 512; }
      else                { int r = e - 31744; src = value; dst = xv; row = r >> 9, k = r & 511; K = 512; }
      float f = src[row * K + k];
      __bf16 hi = (__bf16)f;
      __bf16 lo = (__bf16)(f - (float)hi);
      dst[row * (K << 1) + k]     = hi;
      dst[row * (K << 1) + K + k] = lo;
    }
  }
}

// ---------------------------------------------------------------------------
// Kernel P: all four projections via split-bf16 MFMA. 80 single-wave blocks,
// each computes a 16x64 f32 tile of dst = X @ W + b.
//  blocks [0,24): q (M=48,K2=512)  [24,48): t (M=48,K2=128)
//  blocks [48,64): k (M=32,K2=1024) [64,80): v
// ---------------------------------------------------------------------------
__global__ __launch_bounds__(64) void proj_mfma_kernel(
    const __bf16* __restrict__ xq, const __bf16* __restrict__ xt,
    const __bf16* __restrict__ xk, const __bf16* __restrict__ xv,
    const __bf16* __restrict__ wTq, const __bf16* __restrict__ wTt,
    const __bf16* __restrict__ wTk, const __bf16* __restrict__ wTv,
    const float* __restrict__ bq, const float* __restrict__ bt,
    const float* __restrict__ bk, const float* __restrict__ bv,
    float* __restrict__ qp, float* __restrict__ tp,
    float* __restrict__ kp, float* __restrict__ vp)
{
  int b = blockIdx.x;
  const __bf16 *src, *w; const float* bias; float* dst; int K2, bb;
  if (b < 24)      { src = xq; w = wTq; bias = bq; dst = qp; K2 = 512;  bb = b; }
  else if (b < 48) { src = xt; w = wTt; bias = bt; dst = tp; K2 = 128;  bb = b - 24; }
  else if (b < 64) { src = xk; w = wTk; bias = bk; dst = kp; K2 = 1024; bb = b - 48; }
  else             { src = xv; w = wTv; bias = bv; dst = vp; K2 = 1024; bb = b - 64; }
  int mt = bb >> 3, nt = bb & 7;
  int m0 = mt << 4, n0 = nt << 6;
  int l = threadIdx.x, lhi = l >> 4, llo = l & 15;

  f32x4 acc[4];
  #pragma unroll
  for (int nb = 0; nb < 4; ++nb) acc[nb] = (f32x4){0.f, 0.f, 0.f, 0.f};

  const __bf16* pa = src + (m0 + llo) * K2 + lhi * 8;
  const __bf16* pb = w   + (n0 + llo) * K2 + lhi * 8;

  for (int kc = 0; kc < K2; kc += 32) {
    bf16x8 a = *(const bf16x8*)(pa + kc);
    #pragma unroll
    for (int nb = 0; nb < 4; ++nb) {
      bf16x8 bf = *(const bf16x8*)(pb + nb * 16 * K2 + kc);
      acc[nb] = __builtin_amdgcn_mfma_f32_16x16x32_bf16(a, bf, acc[nb], 0, 0, 0);
    }
  }

  #pragma unroll
  for (int nb = 0; nb < 4; ++nb) {
    int col = n0 + nb * 16 + llo;
    float bias_v = bias[col];
    #pragma unroll
    for (int r = 0; r < 4; ++r) {
      int row = m0 + (lhi << 2) + r;
      dst[row * 512 + col] = acc[nb][r] + bias_v;
    }
  }
}

// ---------------------------------------------------------------------------
// Kernel B: fused two-stage feature-axis attention.
// Grid (m=32, n=48), block 512 = 8 waves (one per head), lane = feature d.
// Writes x split-bf16 rows [1536][1024] ( [0..511]=hi, [512..1023]=lo ).
// ---------------------------------------------------------------------------
__global__ __launch_bounds__(512) void attn_kernel(
    const float* __restrict__ qp, const float* __restrict__ tp,
    const float* __restrict__ kp, const float* __restrict__ vp,
    __bf16* __restrict__ xs)
{
  __shared__ float kl[HH][DK], vl[HH][DK], cvl[HH][DK];
  int m = blockIdx.x, n = blockIdx.y;
  int h = threadIdx.x >> 6, lane = threadIdx.x & 63;

  float kd = kp[m * 512 + h * 64 + lane];
  float vd = vp[m * 512 + h * 64 + lane];
  kl[h][lane] = kd;
  vl[h][lane] = vd;

  float kmax = kd, kmin = kd;
  #pragma unroll
  for (int off = 32; off > 0; off >>= 1) {
    kmax = fmaxf(kmax, __shfl_xor(kmax, off));
    kmin = fminf(kmin, __shfl_xor(kmin, off));
  }
  float a  = qp[n * 512 + h * 64 + lane] * 0.125f;
  float mx = fmaxf(a * kmax, a * kmin);
  __syncthreads();

  float d0 = 0.f, d1 = 0.f, d2 = 0.f, d3 = 0.f;
  float s0 = 0.f, s1 = 0.f, s2 = 0.f, s3 = 0.f;
  #pragma unroll
  for (int j = 0; j < 64; j += 4) {
    float e0 = __expf(fmaf(a, kl[h][j + 0], -mx));
    float e1 = __expf(fmaf(a, kl[h][j + 1], -mx));
    float e2 = __expf(fmaf(a, kl[h][j + 2], -mx));
    float e3 = __expf(fmaf(a, kl[h][j + 3], -mx));
    d0 += e0; d1 += e1; d2 += e2; d3 += e3;
    s0 = fmaf(e0, vl[h][j + 0], s0);
    s1 = fmaf(e1, vl[h][j + 1], s1);
    s2 = fmaf(e2, vl[h][j + 2], s2);
    s3 = fmaf(e3, vl[h][j + 3], s3);
  }
  float cv = ((s0 + s1) + (s2 + s3)) / ((d0 + d1) + (d2 + d3));
  cvl[h][lane] = cv;

  float cmax = cv, cmin = cv;
  #pragma unroll
  for (int off = 32; off > 0; off >>= 1) {
    cmax = fmaxf(cmax, __shfl_xor(cmax, off));
    cmin = fminf(cmin, __shfl_xor(cmin, off));
  }
  float bt2 = tp[n * 512 + h * 64 + lane] * 0.125f;
  float mx2 = fmaxf(bt2 * cmax, bt2 * cmin);
  __syncthreads();

  d0 = d1 = d2 = d3 = 0.f; s0 = s1 = s2 = s3 = 0.f;
  #pragma unroll
  for (int j = 0; j < 64; j += 4) {
    float c0 = cvl[h][j + 0], c1 = cvl[h][j + 1];
    float c2 = cvl[h][j + 2], c3 = cvl[h][j + 3];
    float e0 = __expf(fmaf(bt2, c0, -mx2));
    float e1 = __expf(fmaf(bt2, c1, -mx2));
    float e2 = __expf(fmaf(bt2, c2, -mx2));
    float e3 = __expf(fmaf(bt2, c3, -mx2));
    d0 += e0; d1 += e1; d2 += e2; d3 += e3;
    s0 = fmaf(e0, c0, s0);
    s1 = fmaf(e1, c1, s1);
    s2 = fmaf(e2, c2, s2);
    s3 = fmaf(e3, c3, s3);
  }
  float o = ((s0 + s1) + (s2 + s3)) / ((d0 + d1) + (d2 + d3));

  int row = n * 32 + m;
  int c   = h * 64 + lane;
  __bf16 hi = (__bf16)o;
  __bf16 lo = (__bf16)(o - (float)hi);
  xs[row * 1024 + c]       = hi;
  xs[row * 1024 + 512 + c] = lo;
}

// ---------------------------------------------------------------------------
// Kernel C: out = x @ Wo + bo via split-bf16 MFMA, M=1536 N=512 K2=1024.
// Grid (16,48), 1 wave/block computing a 32x32 tile (2x2 of 16x16x32 MFMA).
// ---------------------------------------------------------------------------
__global__ __launch_bounds__(64) void gemm_out_kernel(
    const __bf16* __restrict__ xs, const __bf16* __restrict__ woT,
    const float* __restrict__ bo, float* __restrict__ out)
{
  int n0 = blockIdx.x << 5;
  int m0 = blockIdx.y << 5;
  int l = threadIdx.x;
  int lhi = l >> 4, llo = l & 15;

  f32x4 acc00 = {0.f, 0.f, 0.f, 0.f};
  f32x4 acc01 = {0.f, 0.f, 0.f, 0.f};
  f32x4 acc10 = {0.f, 0.f, 0.f, 0.f};
  f32x4 acc11 = {0.f, 0.f, 0.f, 0.f};

  const __bf16* pa0 = xs  + (m0 + llo) * 1024 + lhi * 8;
  const __bf16* pa1 = pa0 + 16 * 1024;
  const __bf16* pb0 = woT + (n0 + llo) * 1024 + lhi * 8;
  const __bf16* pb1 = pb0 + 16 * 1024;

  #pragma unroll 4
  for (int kc = 0; kc < 1024; kc += 32) {
    bf16x8 a0 = *(const bf16x8*)(pa0 + kc);
    bf16x8 a1 = *(const bf16x8*)(pa1 + kc);
    bf16x8 b0 = *(const bf16x8*)(pb0 + kc);
    bf16x8 b1 = *(const bf16x8*)(pb1 + kc);
    acc00 = __builtin_amdgcn_mfma_f32_16x16x32_bf16(a0, b0, acc00, 0, 0, 0);
    acc01 = __builtin_amdgcn_mfma_f32_16x16x32_bf16(a0, b1, acc01, 0, 0, 0);
    acc10 = __builtin_amdgcn_mfma_f32_16x16x32_bf16(a1, b0, acc10, 0, 0, 0);
    acc11 = __builtin_amdgcn_mfma_f32_16x16x32_bf16(a1, b1, acc11, 0, 0, 0);
  }

  int colA = n0 + llo, colB = colA + 16;
  float boA = bo[colA], boB = bo[colB];
  #pragma unroll
  for (int r = 0; r < 4; ++r) {
    int rowA = m0 + (lhi << 2) + r;
    int rowB = rowA + 16;
    out[rowA * 512 + colA] = acc00[r] + boA;
    out[rowA * 512 + colB] = acc01[r] + boB;
    out[rowB * 512 + colA] = acc10[r] + boA;
    out[rowB * 512 + colB] = acc11[r] + boB;
  }
}

// ---------------------------------------------------------------------------
extern "C" void kernel_launch(void* const* d_in, const int* in_sizes, int n_in,
                              void* d_out, int out_size, void* d_ws, size_t ws_size,
                              hipStream_t stream) {
  const float* query = (const float*)d_in[0];
  const float* key   = (const float*)d_in[1];
  const float* value = (const float*)d_in[2];
  const float* time_ = (const float*)d_in[3];
  const float* Wq = (const float*)d_in[4];
  const float* bq = (const float*)d_in[5];
  const float* Wt = (const float*)d_in[6];
  const float* bt = (const float*)d_in[7];
  const float* Wk = (const float*)d_in[8];
  const float* bk = (const float*)d_in[9];
  const float* Wv = (const float*)d_in[10];
  const float* bv = (const float*)d_in[11];
  const float* Wo = (const float*)d_in[12];
  const float* bo = (const float*)d_in[13];

  // ws layout (byte offsets, all 16B-aligned):
  char* wsb = (char*)d_ws;
  float*  qp  = (float*) (wsb + 0);        // 48*512 f32
  float*  tp  = (float*) (wsb + 98304);    // 48*512 f32
  float*  kp  = (float*) (wsb + 196608);   // 32*512 f32
  float*  vp  = (float*) (wsb + 262144);   // 32*512 f32
  __bf16* xs  = (__bf16*)(wsb + 327680);   // 1536*1024 bf16
  __bf16* woT = (__bf16*)(wsb + 3473408);  // 512*1024 bf16
  __bf16* xq  = (__bf16*)(wsb + 4521984);  // 48*512
  __bf16* xt  = (__bf16*)(wsb + 4571136);  // 48*128
  __bf16* xk  = (__bf16*)(wsb + 4583424);  // 32*1024
  __bf16* xv  = (__bf16*)(wsb + 4648960);  // 32*1024
  __bf16* wTq = (__bf16*)(wsb + 4714496);  // 512*512
  __bf16* wTt = (__bf16*)(wsb + 5238784);  // 512*128
  __bf16* wTk = (__bf16*)(wsb + 5369856);  // 512*1024
  __bf16* wTv = (__bf16*)(wsb + 6418432);  // 512*1024  (end: 7467008 B)
  float* out = (float*)d_out;

  hipLaunchKernelGGL(split_kernel, dim3(279), dim3(256), 0, stream,
                     query, key, value, time_, Wq, Wt, Wk, Wv, Wo,
                     xq, xt, xk, xv, wTq, wTt, wTk, wTv, woT);
  hipLaunchKernelGGL(proj_mfma_kernel, dim3(80), dim3(64), 0, stream,
                     xq, xt, xk, xv, wTq, wTt, wTk, wTv,
                     bq, bt, bk, bv, qp, tp, kp, vp);
  hipLaunchKernelGGL(attn_kernel, dim3(32, 48), dim3(512), 0, stream,
                     qp, tp, kp, vp, xs);
  hipLaunchKernelGGL(gemm_out_kernel, dim3(16, 48), dim3(64), 0, stream,
                     xs, woT, bo, out);
}

// Round 3
// 53.513 us; speedup vs baseline: 1.5048x; 1.4746x over previous
//
#include <hip/hip_runtime.h>
#include <hip/hip_bf16.h>

// n=48, m=32, d_model=512, H=8, DK=64, d_query=256, d_time=64
typedef __bf16 bf16x8 __attribute__((ext_vector_type(8)));
typedef float f32x4 __attribute__((ext_vector_type(4)));

#if __has_builtin(__builtin_amdgcn_exp2f)
#define EXP2F __builtin_amdgcn_exp2f
#else
#define EXP2F exp2f
#endif

__device__ __forceinline__ float fastrcp(float x) {
#if __has_builtin(__builtin_amdgcn_rcpf)
  return __builtin_amdgcn_rcpf(x);
#else
  return 1.0f / x;
#endif
}

// ---------------------------------------------------------------------------
// Kernel W: weight transpose+split  W[K][512] -> WT[512][2K] ([0,K)=hi,[K,2K)=lo)
// 232 blocks x 256 thr.
// ---------------------------------------------------------------------------
__global__ __launch_bounds__(256) void wsplit_kernel(
    const float* __restrict__ Wq, const float* __restrict__ Wt,
    const float* __restrict__ Wk, const float* __restrict__ Wv,
    const float* __restrict__ Wo,
    __bf16* __restrict__ wTq, __bf16* __restrict__ wTt,
    __bf16* __restrict__ wTk, __bf16* __restrict__ wTv,
    __bf16* __restrict__ woT)
{
  int b = blockIdx.x, t = threadIdx.x;
  const float* W; __bf16* WT; int K, tb;
  if (b < 32)       { W = Wq; WT = wTq; K = 256; tb = b; }
  else if (b < 40)  { W = Wt; WT = wTt; K = 64;  tb = b - 32; }
  else if (b < 104) { W = Wk; WT = wTk; K = 512; tb = b - 40; }
  else if (b < 168) { W = Wv; WT = wTv; K = 512; tb = b - 104; }
  else              { W = Wo; WT = woT; K = 512; tb = b - 168; }
  int kt = tb >> 3, nt = tb & 7;   // 8 n-tiles always (N=512)
  int k0 = kt << 6, n0 = nt << 6;
  __shared__ float tile[64][65];
  #pragma unroll
  for (int e = 0; e < 16; ++e) {
    int idx = t + (e << 8);
    int r = idx >> 6, c = idx & 63;
    tile[r][c] = W[(k0 + r) * 512 + n0 + c];
  }
  __syncthreads();
  int K2 = K << 1;
  #pragma unroll
  for (int e = 0; e < 16; ++e) {
    int idx = t + (e << 8);
    int nn = idx >> 6, kk = idx & 63;
    float f = tile[kk][nn];
    __bf16 hi = (__bf16)f;
    __bf16 lo = (__bf16)(f - (float)hi);
    WT[(n0 + nn) * K2 + k0 + kk]     = hi;
    WT[(n0 + nn) * K2 + K + k0 + kk] = lo;
  }
}

// ---------------------------------------------------------------------------
// Kernel P: projections via split-bf16 MFMA, inline A-split from f32 inputs.
// 80 blocks x 256 thr (4 waves). Each block: one 16x64 output tile; waves
// K-split (chunks of 32 real-k, stride 4), LDS-reduce partials.
//  b[0,24): q (M=48,K=256)  [24,48): t (K=64)  [48,64): k (K=512)  [64,80): v
// ---------------------------------------------------------------------------
__global__ __launch_bounds__(256) void proj_mfma_kernel(
    const float* __restrict__ query, const float* __restrict__ time_,
    const float* __restrict__ key, const float* __restrict__ value,
    const __bf16* __restrict__ wTq, const __bf16* __restrict__ wTt,
    const __bf16* __restrict__ wTk, const __bf16* __restrict__ wTv,
    const float* __restrict__ bq, const float* __restrict__ bt,
    const float* __restrict__ bk, const float* __restrict__ bv,
    float* __restrict__ qp, float* __restrict__ tp,
    float* __restrict__ kp, float* __restrict__ vp)
{
  __shared__ f32x4 red[4][4][64];   // [wave][nb][lane], 16 KB
  int b = blockIdx.x;
  const float* src; const __bf16* wT; const float* bias; float* dst; int K, bb;
  if (b < 24)      { src = query; wT = wTq; bias = bq; dst = qp; K = 256; bb = b; }
  else if (b < 48) { src = time_; wT = wTt; bias = bt; dst = tp; K = 64;  bb = b - 24; }
  else if (b < 64) { src = key;   wT = wTk; bias = bk; dst = kp; K = 512; bb = b - 48; }
  else             { src = value; wT = wTv; bias = bv; dst = vp; K = 512; bb = b - 64; }
  int mt = bb >> 3, nt = bb & 7;
  int m0 = mt << 4, n0 = nt << 6;
  int w = threadIdx.x >> 6;
  int l = threadIdx.x & 63, lhi = l >> 4, llo = l & 15;
  int K2 = K << 1;

  f32x4 acc[4];
  #pragma unroll
  for (int nb = 0; nb < 4; ++nb) acc[nb] = (f32x4){0.f, 0.f, 0.f, 0.f};

  int nkc = K >> 5;
  for (int ci = w; ci < nkc; ci += 4) {
    const float* pa = src + (m0 + llo) * K + (ci << 5) + (lhi << 3);
    f32x4 f0 = *(const f32x4*)pa;
    f32x4 f1 = *(const f32x4*)(pa + 4);
    bf16x8 ahi, alo;
    #pragma unroll
    for (int j = 0; j < 4; ++j) {
      __bf16 h0 = (__bf16)f0[j]; ahi[j]     = h0; alo[j]     = (__bf16)(f0[j] - (float)h0);
      __bf16 h1 = (__bf16)f1[j]; ahi[4 + j] = h1; alo[4 + j] = (__bf16)(f1[j] - (float)h1);
    }
    #pragma unroll
    for (int nb = 0; nb < 4; ++nb) {
      const __bf16* pb = wT + (n0 + (nb << 4) + llo) * K2 + (ci << 5) + (lhi << 3);
      bf16x8 bhi = *(const bf16x8*)pb;
      bf16x8 blo = *(const bf16x8*)(pb + K);
      acc[nb] = __builtin_amdgcn_mfma_f32_16x16x32_bf16(ahi, bhi, acc[nb], 0, 0, 0);
      acc[nb] = __builtin_amdgcn_mfma_f32_16x16x32_bf16(alo, blo, acc[nb], 0, 0, 0);
    }
  }

  #pragma unroll
  for (int nb = 0; nb < 4; ++nb) red[w][nb][l] = acc[nb];
  __syncthreads();

  f32x4 s = red[0][w][l] + red[1][w][l] + red[2][w][l] + red[3][w][l];
  int col = n0 + (w << 4) + llo;
  float bias_v = bias[col];
  #pragma unroll
  for (int r = 0; r < 4; ++r)
    dst[(m0 + (lhi << 2) + r) * 512 + col] = s[r] + bias_v;
}

// ---------------------------------------------------------------------------
// Kernel B: fused two-stage feature-axis attention (no max-sub; exp2-direct).
// Grid (m=32, n=48), 512 thr (wave per head, lane = feature d).
// Writes x split-bf16 rows [1536][1024] ([0,512)=hi, [512,1024)=lo).
// ---------------------------------------------------------------------------
__global__ __launch_bounds__(512) void attn_kernel(
    const float* __restrict__ qp, const float* __restrict__ tp,
    const float* __restrict__ kp, const float* __restrict__ vp,
    __bf16* __restrict__ xs)
{
  __shared__ float cvl[8][64];
  int m = blockIdx.x, n = blockIdx.y;
  int lane = threadIdx.x & 63;
  int hs = __builtin_amdgcn_readfirstlane((int)threadIdx.x) >> 6;  // wave-uniform head

  const float* kk = kp + m * 512 + hs * 64;
  const float* vv = vp + m * 512 + hs * 64;
  const float C = 0.18033688011112042f;  // 0.125 * log2(e)
  float a2 = qp[n * 512 + hs * 64 + lane] * C;

  float den = 0.f, sv = 0.f;
  #pragma unroll
  for (int j4 = 0; j4 < 16; ++j4) {
    f32x4 kq = *(const f32x4*)(kk + (j4 << 2));
    f32x4 vq = *(const f32x4*)(vv + (j4 << 2));
    #pragma unroll
    for (int i = 0; i < 4; ++i) {
      float e = EXP2F(a2 * kq[i]);
      den += e;
      sv = fmaf(e, vq[i], sv);
    }
  }
  float cv = sv * fastrcp(den);
  cvl[hs][lane] = cv;
  float b2 = tp[n * 512 + hs * 64 + lane] * C;
  __syncthreads();

  float den2 = 0.f, sv2 = 0.f;
  #pragma unroll
  for (int j4 = 0; j4 < 16; ++j4) {
    f32x4 c = *(const f32x4*)&cvl[hs][j4 << 2];
    #pragma unroll
    for (int i = 0; i < 4; ++i) {
      float e = EXP2F(b2 * c[i]);
      den2 += e;
      sv2 = fmaf(e, c[i], sv2);
    }
  }
  float o = sv2 * fastrcp(den2);

  int row = n * 32 + m;
  int c0 = hs * 64 + lane;
  __bf16 hi = (__bf16)o;
  __bf16 lo = (__bf16)(o - (float)hi);
  xs[row * 1024 + c0]       = hi;
  xs[row * 1024 + 512 + c0] = lo;
}

// ---------------------------------------------------------------------------
// Kernel C: out = x @ Wo + bo via split-bf16 MFMA, M=1536 N=512 K2=1024.
// Grid (16,48), 1 wave/block, 32x32 tile (2x2 of 16x16x32 MFMA).
// ---------------------------------------------------------------------------
__global__ __launch_bounds__(64) void gemm_out_kernel(
    const __bf16* __restrict__ xs, const __bf16* __restrict__ woT,
    const float* __restrict__ bo, float* __restrict__ out)
{
  int n0 = blockIdx.x << 5;
  int m0 = blockIdx.y << 5;
  int l = threadIdx.x;
  int lhi = l >> 4, llo = l & 15;

  f32x4 acc00 = {0.f, 0.f, 0.f, 0.f};
  f32x4 acc01 = {0.f, 0.f, 0.f, 0.f};
  f32x4 acc10 = {0.f, 0.f, 0.f, 0.f};
  f32x4 acc11 = {0.f, 0.f, 0.f, 0.f};

  const __bf16* pa0 = xs  + (m0 + llo) * 1024 + lhi * 8;
  const __bf16* pa1 = pa0 + 16 * 1024;
  const __bf16* pb0 = woT + (n0 + llo) * 1024 + lhi * 8;
  const __bf16* pb1 = pb0 + 16 * 1024;

  #pragma unroll 4
  for (int kc = 0; kc < 1024; kc += 32) {
    bf16x8 a0 = *(const bf16x8*)(pa0 + kc);
    bf16x8 a1 = *(const bf16x8*)(pa1 + kc);
    bf16x8 b0 = *(const bf16x8*)(pb0 + kc);
    bf16x8 b1 = *(const bf16x8*)(pb1 + kc);
    acc00 = __builtin_amdgcn_mfma_f32_16x16x32_bf16(a0, b0, acc00, 0, 0, 0);
    acc01 = __builtin_amdgcn_mfma_f32_16x16x32_bf16(a0, b1, acc01, 0, 0, 0);
    acc10 = __builtin_amdgcn_mfma_f32_16x16x32_bf16(a1, b0, acc10, 0, 0, 0);
    acc11 = __builtin_amdgcn_mfma_f32_16x16x32_bf16(a1, b1, acc11, 0, 0, 0);
  }

  int colA = n0 + llo, colB = colA + 16;
  float boA = bo[colA], boB = bo[colB];
  #pragma unroll
  for (int r = 0; r < 4; ++r) {
    int rowA = m0 + (lhi << 2) + r;
    int rowB = rowA + 16;
    out[rowA * 512 + colA] = acc00[r] + boA;
    out[rowA * 512 + colB] = acc01[r] + boB;
    out[rowB * 512 + colA] = acc10[r] + boA;
    out[rowB * 512 + colB] = acc11[r] + boB;
  }
}

// ---------------------------------------------------------------------------
extern "C" void kernel_launch(void* const* d_in, const int* in_sizes, int n_in,
                              void* d_out, int out_size, void* d_ws, size_t ws_size,
                              hipStream_t stream) {
  const float* query = (const float*)d_in[0];
  const float* key   = (const float*)d_in[1];
  const float* value = (const float*)d_in[2];
  const float* time_ = (const float*)d_in[3];
  const float* Wq = (const float*)d_in[4];
  const float* bq = (const float*)d_in[5];
  const float* Wt = (const float*)d_in[6];
  const float* bt = (const float*)d_in[7];
  const float* Wk = (const float*)d_in[8];
  const float* bk = (const float*)d_in[9];
  const float* Wv = (const float*)d_in[10];
  const float* bv = (const float*)d_in[11];
  const float* Wo = (const float*)d_in[12];
  const float* bo = (const float*)d_in[13];

  // ws layout (byte offsets, 16B-aligned):
  char* wsb = (char*)d_ws;
  float*  qp  = (float*) (wsb + 0);        // 48*512 f32
  float*  tp  = (float*) (wsb + 98304);    // 48*512 f32
  float*  kp  = (float*) (wsb + 196608);   // 32*512 f32
  float*  vp  = (float*) (wsb + 262144);   // 32*512 f32
  __bf16* xs  = (__bf16*)(wsb + 327680);   // 1536*1024 bf16
  __bf16* woT = (__bf16*)(wsb + 3473408);  // 512*1024 bf16
  __bf16* wTq = (__bf16*)(wsb + 4521984);  // 512*512
  __bf16* wTt = (__bf16*)(wsb + 5046272);  // 512*128
  __bf16* wTk = (__bf16*)(wsb + 5177344);  // 512*1024
  __bf16* wTv = (__bf16*)(wsb + 6225920);  // 512*1024 (end 7274496 B)
  float* out = (float*)d_out;

  hipLaunchKernelGGL(wsplit_kernel, dim3(232), dim3(256), 0, stream,
                     Wq, Wt, Wk, Wv, Wo, wTq, wTt, wTk, wTv, woT);
  hipLaunchKernelGGL(proj_mfma_kernel, dim3(80), dim3(256), 0, stream,
                     query, time_, key, value, wTq, wTt, wTk, wTv,
                     bq, bt, bk, bv, qp, tp, kp, vp);
  hipLaunchKernelGGL(attn_kernel, dim3(32, 48), dim3(512), 0, stream,
                     qp, tp, kp, vp, xs);
  hipLaunchKernelGGL(gemm_out_kernel, dim3(16, 48), dim3(64), 0, stream,
                     xs, woT, bo, out);
}

// Round 4
// 45.739 us; speedup vs baseline: 1.7606x; 1.1700x over previous
//
#include <hip/hip_runtime.h>
#include <hip/hip_bf16.h>

// n=48, m=32, d_model=512, H=8, DK=64, d_query=256, d_time=64
typedef __bf16 bf16x8 __attribute__((ext_vector_type(8)));
typedef float f32x4 __attribute__((ext_vector_type(4)));

#if __has_builtin(__builtin_amdgcn_exp2f)
#define EXP2F __builtin_amdgcn_exp2f
#else
#define EXP2F exp2f
#endif

__device__ __forceinline__ float fastrcp(float x) {
#if __has_builtin(__builtin_amdgcn_rcpf)
  return __builtin_amdgcn_rcpf(x);
#else
  return 1.0f / x;
#endif
}

// ---------------------------------------------------------------------------
// Kernel 1: fused projections (inline W transpose+split via wave-private LDS)
//           + Wo transpose/split for the output GEMM.
// 144 blocks x 256 thr:
//   b [0,24):  q-proj (M=48, K=256)   [24,48): t-proj (K=64)
//   b [48,64): k-proj (M=32, K=512)   [64,80): v-proj (K=512)
//   b [80,144): Wo split -> woT[512][1024]
// proj block: 16m x 64n f32 tile of dst = X @ W + b. Waves K-split (32-k
// chunks, stride 4); per chunk each wave stages W[kchunk][n0:n0+64] as
// split-bf16 in its private LDS region (fragment layout), MFMAs, then
// LDS-reduce across waves.
// ---------------------------------------------------------------------------
__global__ __launch_bounds__(256) void proj_wsplit_kernel(
    const float* __restrict__ query, const float* __restrict__ time_,
    const float* __restrict__ key, const float* __restrict__ value,
    const float* __restrict__ Wq, const float* __restrict__ Wt,
    const float* __restrict__ Wk, const float* __restrict__ Wv,
    const float* __restrict__ Wo,
    const float* __restrict__ bq, const float* __restrict__ bt,
    const float* __restrict__ bk, const float* __restrict__ bv,
    float* __restrict__ qp, float* __restrict__ tp,
    float* __restrict__ kp, float* __restrict__ vp,
    __bf16* __restrict__ woT)
{
  __shared__ char smem[57344];  // proj: ldsH 20480 | ldsL 20480 | red 16384
  int b = blockIdx.x, t = threadIdx.x;

  if (b >= 80) {
    // ---- Wo transpose + split (f32 -> bf16 hi|lo), K=512 -> woT[512][1024]
    float (*tile)[65] = (float(*)[65])smem;  // 64x65 f32 = 16640 B
    int tb = b - 80;
    int kt = tb >> 3, nt = tb & 7;
    int k0 = kt << 6, n0 = nt << 6;
    #pragma unroll
    for (int e = 0; e < 16; ++e) {
      int idx = t + (e << 8);
      int r = idx >> 6, c = idx & 63;
      tile[r][c] = Wo[(k0 + r) * 512 + n0 + c];
    }
    __syncthreads();
    #pragma unroll
    for (int e = 0; e < 16; ++e) {
      int idx = t + (e << 8);
      int nn = idx >> 6, kk = idx & 63;
      float f = tile[kk][nn];
      __bf16 hi = (__bf16)f;
      __bf16 lo = (__bf16)(f - (float)hi);
      woT[(n0 + nn) * 1024 + k0 + kk]       = hi;
      woT[(n0 + nn) * 1024 + 512 + k0 + kk] = lo;
    }
    return;
  }

  // ---- projections
  __bf16 (*ldsH)[64][40] = (__bf16(*)[64][40])(smem);          // [wave][n][k]
  __bf16 (*ldsL)[64][40] = (__bf16(*)[64][40])(smem + 20480);
  f32x4 (*red)[4][64]    = (f32x4(*)[4][64])(smem + 40960);    // [wave][nb][lane]

  const float* src; const float* W; const float* bias; float* dst; int K, bb;
  if (b < 24)      { src = query; W = Wq; bias = bq; dst = qp; K = 256; bb = b; }
  else if (b < 48) { src = time_; W = Wt; bias = bt; dst = tp; K = 64;  bb = b - 24; }
  else if (b < 64) { src = key;   W = Wk; bias = bk; dst = kp; K = 512; bb = b - 48; }
  else             { src = value; W = Wv; bias = bv; dst = vp; K = 512; bb = b - 64; }
  int mt = bb >> 3, nt = bb & 7;
  int m0 = mt << 4, n0 = nt << 6;
  int w = t >> 6;
  int l = t & 63, lhi = l >> 4, llo = l & 15;

  f32x4 acc[4];
  #pragma unroll
  for (int nb = 0; nb < 4; ++nb) acc[nb] = (f32x4){0.f, 0.f, 0.f, 0.f};

  int nkc = K >> 5;
  for (int ci = w; ci < nkc; ci += 4) {
    int cbase = ci << 5;
    // stage W[cbase..cbase+32)[n0..n0+64) -> wave-private LDS (split-bf16),
    // layout ldsH[w][n][k] so fragment reads are contiguous b128.
    #pragma unroll
    for (int k8 = 0; k8 < 4; ++k8) {
      const float* wp = W + (cbase + (k8 << 3)) * 512 + n0 + l;
      bf16x8 hv, lv;
      #pragma unroll
      for (int j = 0; j < 8; ++j) {
        float f = wp[j * 512];          // coalesced: lanes span 64 consecutive cols
        __bf16 h = (__bf16)f;
        hv[j] = h;
        lv[j] = (__bf16)(f - (float)h);
      }
      *(bf16x8*)&ldsH[w][l][k8 << 3] = hv;
      *(bf16x8*)&ldsL[w][l][k8 << 3] = lv;
    }
    // A fragment: split f32 input in-register
    const float* pa = src + (m0 + llo) * K + cbase + (lhi << 3);
    f32x4 f0 = *(const f32x4*)pa;
    f32x4 f1 = *(const f32x4*)(pa + 4);
    bf16x8 ahi, alo;
    #pragma unroll
    for (int j = 0; j < 4; ++j) {
      __bf16 h0 = (__bf16)f0[j]; ahi[j]     = h0; alo[j]     = (__bf16)(f0[j] - (float)h0);
      __bf16 h1 = (__bf16)f1[j]; ahi[4 + j] = h1; alo[4 + j] = (__bf16)(f1[j] - (float)h1);
    }
    #pragma unroll
    for (int nb = 0; nb < 4; ++nb) {
      int n = (nb << 4) + llo;
      bf16x8 bhi = *(const bf16x8*)&ldsH[w][n][lhi << 3];
      bf16x8 blo = *(const bf16x8*)&ldsL[w][n][lhi << 3];
      acc[nb] = __builtin_amdgcn_mfma_f32_16x16x32_bf16(ahi, bhi, acc[nb], 0, 0, 0);
      acc[nb] = __builtin_amdgcn_mfma_f32_16x16x32_bf16(alo, blo, acc[nb], 0, 0, 0);
    }
  }

  __syncthreads();  // ldsH/L done everywhere; red region is separate anyway
  #pragma unroll
  for (int nb = 0; nb < 4; ++nb) red[w][nb][l] = acc[nb];
  __syncthreads();

  f32x4 s = red[0][w][l] + red[1][w][l] + red[2][w][l] + red[3][w][l];
  int col = n0 + (w << 4) + llo;
  float bias_v = bias[col];
  #pragma unroll
  for (int r = 0; r < 4; ++r)
    dst[(m0 + (lhi << 2) + r) * 512 + col] = s[r] + bias_v;
}

// ---------------------------------------------------------------------------
// Kernel 2: fused two-stage feature-axis attention (no max-sub; exp2-direct).
// Grid (m=32, n=48), 512 thr (wave per head, lane = feature d).
// Writes x split-bf16 rows [1536][1024] ([0,512)=hi, [512,1024)=lo).
// ---------------------------------------------------------------------------
__global__ __launch_bounds__(512) void attn_kernel(
    const float* __restrict__ qp, const float* __restrict__ tp,
    const float* __restrict__ kp, const float* __restrict__ vp,
    __bf16* __restrict__ xs)
{
  __shared__ float cvl[8][64];
  int m = blockIdx.x, n = blockIdx.y;
  int lane = threadIdx.x & 63;
  int hs = __builtin_amdgcn_readfirstlane((int)threadIdx.x) >> 6;

  const float* kk = kp + m * 512 + hs * 64;
  const float* vv = vp + m * 512 + hs * 64;
  const float C = 0.18033688011112042f;  // 0.125 * log2(e)
  float a2 = qp[n * 512 + hs * 64 + lane] * C;

  float den = 0.f, sv = 0.f;
  #pragma unroll
  for (int j4 = 0; j4 < 16; ++j4) {
    f32x4 kq = *(const f32x4*)(kk + (j4 << 2));
    f32x4 vq = *(const f32x4*)(vv + (j4 << 2));
    #pragma unroll
    for (int i = 0; i < 4; ++i) {
      float e = EXP2F(a2 * kq[i]);
      den += e;
      sv = fmaf(e, vq[i], sv);
    }
  }
  float cv = sv * fastrcp(den);
  cvl[hs][lane] = cv;
  float b2 = tp[n * 512 + hs * 64 + lane] * C;
  __syncthreads();

  float den2 = 0.f, sv2 = 0.f;
  #pragma unroll
  for (int j4 = 0; j4 < 16; ++j4) {
    f32x4 c = *(const f32x4*)&cvl[hs][j4 << 2];
    #pragma unroll
    for (int i = 0; i < 4; ++i) {
      float e = EXP2F(b2 * c[i]);
      den2 += e;
      sv2 = fmaf(e, c[i], sv2);
    }
  }
  float o = sv2 * fastrcp(den2);

  int row = n * 32 + m;
  int c0 = hs * 64 + lane;
  __bf16 hi = (__bf16)o;
  __bf16 lo = (__bf16)(o - (float)hi);
  xs[row * 1024 + c0]       = hi;
  xs[row * 1024 + 512 + c0] = lo;
}

// ---------------------------------------------------------------------------
// Kernel 3: out = x @ Wo + bo via split-bf16 MFMA, M=1536 N=512 K2=1024.
// Grid (4,48) x 256 thr: block tile 32m x 128n; wave w owns 32x32 tile at
// n = bx*128 + w*32 (A-fragments shared across waves through L1).
// ---------------------------------------------------------------------------
__global__ __launch_bounds__(256) void gemm_out_kernel(
    const __bf16* __restrict__ xs, const __bf16* __restrict__ woT,
    const float* __restrict__ bo, float* __restrict__ out)
{
  int w = threadIdx.x >> 6;
  int n0 = (blockIdx.x << 7) + (w << 5);
  int m0 = blockIdx.y << 5;
  int l = threadIdx.x & 63;
  int lhi = l >> 4, llo = l & 15;

  f32x4 acc00 = {0.f, 0.f, 0.f, 0.f};
  f32x4 acc01 = {0.f, 0.f, 0.f, 0.f};
  f32x4 acc10 = {0.f, 0.f, 0.f, 0.f};
  f32x4 acc11 = {0.f, 0.f, 0.f, 0.f};

  const __bf16* pa0 = xs  + (m0 + llo) * 1024 + (lhi << 3);
  const __bf16* pa1 = pa0 + 16 * 1024;
  const __bf16* pb0 = woT + (n0 + llo) * 1024 + (lhi << 3);
  const __bf16* pb1 = pb0 + 16 * 1024;

  #pragma unroll 4
  for (int kc = 0; kc < 1024; kc += 32) {
    bf16x8 a0 = *(const bf16x8*)(pa0 + kc);
    bf16x8 a1 = *(const bf16x8*)(pa1 + kc);
    bf16x8 b0 = *(const bf16x8*)(pb0 + kc);
    bf16x8 b1 = *(const bf16x8*)(pb1 + kc);
    acc00 = __builtin_amdgcn_mfma_f32_16x16x32_bf16(a0, b0, acc00, 0, 0, 0);
    acc01 = __builtin_amdgcn_mfma_f32_16x16x32_bf16(a0, b1, acc01, 0, 0, 0);
    acc10 = __builtin_amdgcn_mfma_f32_16x16x32_bf16(a1, b0, acc10, 0, 0, 0);
    acc11 = __builtin_amdgcn_mfma_f32_16x16x32_bf16(a1, b1, acc11, 0, 0, 0);
  }

  int colA = n0 + llo, colB = colA + 16;
  float boA = bo[colA], boB = bo[colB];
  #pragma unroll
  for (int r = 0; r < 4; ++r) {
    int rowA = m0 + (lhi << 2) + r;
    int rowB = rowA + 16;
    out[rowA * 512 + colA] = acc00[r] + boA;
    out[rowA * 512 + colB] = acc01[r] + boB;
    out[rowB * 512 + colA] = acc10[r] + boA;
    out[rowB * 512 + colB] = acc11[r] + boB;
  }
}

// ---------------------------------------------------------------------------
extern "C" void kernel_launch(void* const* d_in, const int* in_sizes, int n_in,
                              void* d_out, int out_size, void* d_ws, size_t ws_size,
                              hipStream_t stream) {
  const float* query = (const float*)d_in[0];
  const float* key   = (const float*)d_in[1];
  const float* value = (const float*)d_in[2];
  const float* time_ = (const float*)d_in[3];
  const float* Wq = (const float*)d_in[4];
  const float* bq = (const float*)d_in[5];
  const float* Wt = (const float*)d_in[6];
  const float* bt = (const float*)d_in[7];
  const float* Wk = (const float*)d_in[8];
  const float* bk = (const float*)d_in[9];
  const float* Wv = (const float*)d_in[10];
  const float* bv = (const float*)d_in[11];
  const float* Wo = (const float*)d_in[12];
  const float* bo = (const float*)d_in[13];

  // ws layout (byte offsets, 16B-aligned):
  char* wsb = (char*)d_ws;
  float*  qp  = (float*) (wsb + 0);        // 48*512 f32
  float*  tp  = (float*) (wsb + 98304);    // 48*512 f32
  float*  kp  = (float*) (wsb + 196608);   // 32*512 f32
  float*  vp  = (float*) (wsb + 262144);   // 32*512 f32
  __bf16* xs  = (__bf16*)(wsb + 327680);   // 1536*1024 bf16
  __bf16* woT = (__bf16*)(wsb + 3473408);  // 512*1024 bf16 (end 4521984 B)
  float* out = (float*)d_out;

  hipLaunchKernelGGL(proj_wsplit_kernel, dim3(144), dim3(256), 0, stream,
                     query, time_, key, value, Wq, Wt, Wk, Wv, Wo,
                     bq, bt, bk, bv, qp, tp, kp, vp, woT);
  hipLaunchKernelGGL(attn_kernel, dim3(32, 48), dim3(512), 0, stream,
                     qp, tp, kp, vp, xs);
  hipLaunchKernelGGL(gemm_out_kernel, dim3(4, 48), dim3(256), 0, stream,
                     xs, woT, bo, out);
}

// Round 5
// 36.504 us; speedup vs baseline: 2.2060x; 1.2530x over previous
//
#include <hip/hip_runtime.h>
#include <hip/hip_bf16.h>

// n=48, m=32, d_model=512, H=8, DK=64, d_query=256, d_time=64
typedef __bf16 bf16x8 __attribute__((ext_vector_type(8)));
typedef float f32x4 __attribute__((ext_vector_type(4)));
typedef float f32x2 __attribute__((ext_vector_type(2)));

#if __has_builtin(__builtin_amdgcn_exp2f)
#define EXP2F __builtin_amdgcn_exp2f
#else
#define EXP2F exp2f
#endif

__device__ __forceinline__ float fastrcp(float x) {
#if __has_builtin(__builtin_amdgcn_rcpf)
  return __builtin_amdgcn_rcpf(x);
#else
  return 1.0f / x;
#endif
}

__device__ __forceinline__ f32x2 exp2_pk(f32x2 t) {
  return (f32x2){EXP2F(t[0]), EXP2F(t[1])};
}

// ---------------------------------------------------------------------------
// Kernel 1: fused projections (inline W transpose+split via wave-private LDS)
//           + Wo transpose/split for the output GEMM.
// 144 blocks x 256 thr:
//   b [0,24):  q-proj (M=48, K=256)   [24,48): t-proj (K=64)
//   b [48,64): k-proj (M=32, K=512)   [64,80): v-proj (K=512)
//   b [80,144): Wo split -> woT[512][1024] (hi|lo)
// ---------------------------------------------------------------------------
__global__ __launch_bounds__(256) void proj_wsplit_kernel(
    const float* __restrict__ query, const float* __restrict__ time_,
    const float* __restrict__ key, const float* __restrict__ value,
    const float* __restrict__ Wq, const float* __restrict__ Wt,
    const float* __restrict__ Wk, const float* __restrict__ Wv,
    const float* __restrict__ Wo,
    const float* __restrict__ bq, const float* __restrict__ bt,
    const float* __restrict__ bk, const float* __restrict__ bv,
    float* __restrict__ qp, float* __restrict__ tp,
    float* __restrict__ kp, float* __restrict__ vp,
    __bf16* __restrict__ woT)
{
  __shared__ char smem[57344];  // proj: ldsH 20480 | ldsL 20480 | red 16384
  int b = blockIdx.x, t = threadIdx.x;

  if (b >= 80) {
    // ---- Wo transpose + split (f32 -> bf16 hi|lo), K=512 -> woT[512][1024]
    float (*tile)[65] = (float(*)[65])smem;  // 64x65 f32
    int tb = b - 80;
    int kt = tb >> 3, nt = tb & 7;
    int k0 = kt << 6, n0 = nt << 6;
    #pragma unroll
    for (int e = 0; e < 16; ++e) {
      int idx = t + (e << 8);
      int r = idx >> 6, c = idx & 63;
      tile[r][c] = Wo[(k0 + r) * 512 + n0 + c];
    }
    __syncthreads();
    #pragma unroll
    for (int e = 0; e < 16; ++e) {
      int idx = t + (e << 8);
      int nn = idx >> 6, kk = idx & 63;
      float f = tile[kk][nn];
      __bf16 hi = (__bf16)f;
      __bf16 lo = (__bf16)(f - (float)hi);
      woT[(n0 + nn) * 1024 + k0 + kk]       = hi;
      woT[(n0 + nn) * 1024 + 512 + k0 + kk] = lo;
    }
    return;
  }

  // ---- projections
  __bf16 (*ldsH)[64][40] = (__bf16(*)[64][40])(smem);          // [wave][n][k]
  __bf16 (*ldsL)[64][40] = (__bf16(*)[64][40])(smem + 20480);
  f32x4 (*red)[4][64]    = (f32x4(*)[4][64])(smem + 40960);    // [wave][nb][lane]

  const float* src; const float* W; const float* bias; float* dst; int K, bb;
  if (b < 24)      { src = query; W = Wq; bias = bq; dst = qp; K = 256; bb = b; }
  else if (b < 48) { src = time_; W = Wt; bias = bt; dst = tp; K = 64;  bb = b - 24; }
  else if (b < 64) { src = key;   W = Wk; bias = bk; dst = kp; K = 512; bb = b - 48; }
  else             { src = value; W = Wv; bias = bv; dst = vp; K = 512; bb = b - 64; }
  int mt = bb >> 3, nt = bb & 7;
  int m0 = mt << 4, n0 = nt << 6;
  int w = t >> 6;
  int l = t & 63, lhi = l >> 4, llo = l & 15;

  f32x4 acc[4];
  #pragma unroll
  for (int nb = 0; nb < 4; ++nb) acc[nb] = (f32x4){0.f, 0.f, 0.f, 0.f};

  int nkc = K >> 5;
  for (int ci = w; ci < nkc; ci += 4) {
    int cbase = ci << 5;
    #pragma unroll
    for (int k8 = 0; k8 < 4; ++k8) {
      const float* wp = W + (cbase + (k8 << 3)) * 512 + n0 + l;
      bf16x8 hv, lv;
      #pragma unroll
      for (int j = 0; j < 8; ++j) {
        float f = wp[j * 512];          // coalesced: lanes span 64 consecutive cols
        __bf16 h = (__bf16)f;
        hv[j] = h;
        lv[j] = (__bf16)(f - (float)h);
      }
      *(bf16x8*)&ldsH[w][l][k8 << 3] = hv;
      *(bf16x8*)&ldsL[w][l][k8 << 3] = lv;
    }
    const float* pa = src + (m0 + llo) * K + cbase + (lhi << 3);
    f32x4 f0 = *(const f32x4*)pa;
    f32x4 f1 = *(const f32x4*)(pa + 4);
    bf16x8 ahi, alo;
    #pragma unroll
    for (int j = 0; j < 4; ++j) {
      __bf16 h0 = (__bf16)f0[j]; ahi[j]     = h0; alo[j]     = (__bf16)(f0[j] - (float)h0);
      __bf16 h1 = (__bf16)f1[j]; ahi[4 + j] = h1; alo[4 + j] = (__bf16)(f1[j] - (float)h1);
    }
    #pragma unroll
    for (int nb = 0; nb < 4; ++nb) {
      int n = (nb << 4) + llo;
      bf16x8 bhi = *(const bf16x8*)&ldsH[w][n][lhi << 3];
      bf16x8 blo = *(const bf16x8*)&ldsL[w][n][lhi << 3];
      acc[nb] = __builtin_amdgcn_mfma_f32_16x16x32_bf16(ahi, bhi, acc[nb], 0, 0, 0);
      acc[nb] = __builtin_amdgcn_mfma_f32_16x16x32_bf16(alo, blo, acc[nb], 0, 0, 0);
    }
  }

  __syncthreads();
  #pragma unroll
  for (int nb = 0; nb < 4; ++nb) red[w][nb][l] = acc[nb];
  __syncthreads();

  f32x4 s = red[0][w][l] + red[1][w][l] + red[2][w][l] + red[3][w][l];
  int col = n0 + (w << 4) + llo;
  float bias_v = bias[col];
  #pragma unroll
  for (int r = 0; r < 4; ++r)
    dst[(m0 + (lhi << 2) + r) * 512 + col] = s[r] + bias_v;
}

// ---------------------------------------------------------------------------
// Kernel 2: fused two-stage feature-axis attention.
// Packed-f32 inner loops (v_pk_mul/add/fma), exp2-direct, no max-sub.
// Grid (m=32, n=48), 512 thr (wave per head, lane = feature d).
// cvl is wave-local (cvl[hs] written+read only by wave hs) -> no barrier.
// Writes x as plain bf16 rows xs[1536][512].
// ---------------------------------------------------------------------------
__global__ __launch_bounds__(512) void attn_kernel(
    const float* __restrict__ qp, const float* __restrict__ tp,
    const float* __restrict__ kp, const float* __restrict__ vp,
    __bf16* __restrict__ xs)
{
  __shared__ float cvl[8][64];
  int m = blockIdx.x, n = blockIdx.y;
  int lane = threadIdx.x & 63;
  int hs = __builtin_amdgcn_readfirstlane((int)threadIdx.x) >> 6;

  const float* kk = kp + m * 512 + hs * 64;
  const float* vv = vp + m * 512 + hs * 64;
  const float C = 0.18033688011112042f;  // 0.125 * log2(e)
  float a2 = qp[n * 512 + hs * 64 + lane] * C;
  float b2 = tp[n * 512 + hs * 64 + lane] * C;  // hoisted: hides load latency

  f32x2 a2p = {a2, a2};
  f32x2 den = {0.f, 0.f}, sv = {0.f, 0.f};
  #pragma unroll
  for (int j4 = 0; j4 < 16; ++j4) {
    f32x4 kq = *(const f32x4*)(kk + (j4 << 2));
    f32x4 vq = *(const f32x4*)(vv + (j4 << 2));
    f32x2 klo = {kq[0], kq[1]}, khi = {kq[2], kq[3]};
    f32x2 vlo = {vq[0], vq[1]}, vhi = {vq[2], vq[3]};
    f32x2 e0 = exp2_pk(a2p * klo);
    f32x2 e1 = exp2_pk(a2p * khi);
    den += e0 + e1;
    sv += e0 * vlo;   // v_pk_fma_f32
    sv += e1 * vhi;
  }
  float cv = (sv[0] + sv[1]) * fastrcp(den[0] + den[1]);
  cvl[hs][lane] = cv;   // wave-local: compiler's lgkmcnt wait is sufficient

  f32x2 b2p = {b2, b2};
  f32x2 den2 = {0.f, 0.f}, sv2 = {0.f, 0.f};
  #pragma unroll
  for (int j4 = 0; j4 < 16; ++j4) {
    f32x4 c = *(const f32x4*)&cvl[hs][j4 << 2];
    f32x2 clo = {c[0], c[1]}, chi = {c[2], c[3]};
    f32x2 e0 = exp2_pk(b2p * clo);
    f32x2 e1 = exp2_pk(b2p * chi);
    den2 += e0 + e1;
    sv2 += e0 * clo;
    sv2 += e1 * chi;
  }
  float o = (sv2[0] + sv2[1]) * fastrcp(den2[0] + den2[1]);

  xs[(n * 32 + m) * 512 + hs * 64 + lane] = (__bf16)o;
}

// ---------------------------------------------------------------------------
// Kernel 3: out = x @ Wo + bo; x plain bf16 (K=512), Wo split (hi+lo MFMA
// pairs share the A fragment). Grid (4,48) x 256: block 32m x 128n, wave w
// owns the 32x32 tile at n = bx*128 + w*32.
// ---------------------------------------------------------------------------
__global__ __launch_bounds__(256) void gemm_out_kernel(
    const __bf16* __restrict__ xs, const __bf16* __restrict__ woT,
    const float* __restrict__ bo, float* __restrict__ out)
{
  int w = threadIdx.x >> 6;
  int n0 = (blockIdx.x << 7) + (w << 5);
  int m0 = blockIdx.y << 5;
  int l = threadIdx.x & 63;
  int lhi = l >> 4, llo = l & 15;

  f32x4 acc00 = {0.f, 0.f, 0.f, 0.f};
  f32x4 acc01 = {0.f, 0.f, 0.f, 0.f};
  f32x4 acc10 = {0.f, 0.f, 0.f, 0.f};
  f32x4 acc11 = {0.f, 0.f, 0.f, 0.f};

  const __bf16* pa0  = xs  + (m0 + llo) * 512 + (lhi << 3);
  const __bf16* pa1  = pa0 + 16 * 512;
  const __bf16* pbh0 = woT + (n0 + llo) * 1024 + (lhi << 3);
  const __bf16* pbh1 = pbh0 + 16 * 1024;

  #pragma unroll 4
  for (int kc = 0; kc < 512; kc += 32) {
    bf16x8 a0  = *(const bf16x8*)(pa0 + kc);
    bf16x8 a1  = *(const bf16x8*)(pa1 + kc);
    bf16x8 bh0 = *(const bf16x8*)(pbh0 + kc);
    bf16x8 bl0 = *(const bf16x8*)(pbh0 + 512 + kc);
    bf16x8 bh1 = *(const bf16x8*)(pbh1 + kc);
    bf16x8 bl1 = *(const bf16x8*)(pbh1 + 512 + kc);
    acc00 = __builtin_amdgcn_mfma_f32_16x16x32_bf16(a0, bh0, acc00, 0, 0, 0);
    acc01 = __builtin_amdgcn_mfma_f32_16x16x32_bf16(a0, bh1, acc01, 0, 0, 0);
    acc10 = __builtin_amdgcn_mfma_f32_16x16x32_bf16(a1, bh0, acc10, 0, 0, 0);
    acc11 = __builtin_amdgcn_mfma_f32_16x16x32_bf16(a1, bh1, acc11, 0, 0, 0);
    acc00 = __builtin_amdgcn_mfma_f32_16x16x32_bf16(a0, bl0, acc00, 0, 0, 0);
    acc01 = __builtin_amdgcn_mfma_f32_16x16x32_bf16(a0, bl1, acc01, 0, 0, 0);
    acc10 = __builtin_amdgcn_mfma_f32_16x16x32_bf16(a1, bl0, acc10, 0, 0, 0);
    acc11 = __builtin_amdgcn_mfma_f32_16x16x32_bf16(a1, bl1, acc11, 0, 0, 0);
  }

  int colA = n0 + llo, colB = colA + 16;
  float boA = bo[colA], boB = bo[colB];
  #pragma unroll
  for (int r = 0; r < 4; ++r) {
    int rowA = m0 + (lhi << 2) + r;
    int rowB = rowA + 16;
    out[rowA * 512 + colA] = acc00[r] + boA;
    out[rowA * 512 + colB] = acc01[r] + boB;
    out[rowB * 512 + colA] = acc10[r] + boA;
    out[rowB * 512 + colB] = acc11[r] + boB;
  }
}

// ---------------------------------------------------------------------------
extern "C" void kernel_launch(void* const* d_in, const int* in_sizes, int n_in,
                              void* d_out, int out_size, void* d_ws, size_t ws_size,
                              hipStream_t stream) {
  const float* query = (const float*)d_in[0];
  const float* key   = (const float*)d_in[1];
  const float* value = (const float*)d_in[2];
  const float* time_ = (const float*)d_in[3];
  const float* Wq = (const float*)d_in[4];
  const float* bq = (const float*)d_in[5];
  const float* Wt = (const float*)d_in[6];
  const float* bt = (const float*)d_in[7];
  const float* Wk = (const float*)d_in[8];
  const float* bk = (const float*)d_in[9];
  const float* Wv = (const float*)d_in[10];
  const float* bv = (const float*)d_in[11];
  const float* Wo = (const float*)d_in[12];
  const float* bo = (const float*)d_in[13];

  // ws layout (byte offsets, 16B-aligned):
  char* wsb = (char*)d_ws;
  float*  qp  = (float*) (wsb + 0);        // 48*512 f32
  float*  tp  = (float*) (wsb + 98304);    // 48*512 f32
  float*  kp  = (float*) (wsb + 196608);   // 32*512 f32
  float*  vp  = (float*) (wsb + 262144);   // 32*512 f32
  __bf16* xs  = (__bf16*)(wsb + 327680);   // 1536*512 bf16
  __bf16* woT = (__bf16*)(wsb + 1900544);  // 512*1024 bf16 (end 2949120 B)
  float* out = (float*)d_out;

  hipLaunchKernelGGL(proj_wsplit_kernel, dim3(144), dim3(256), 0, stream,
                     query, time_, key, value, Wq, Wt, Wk, Wv, Wo,
                     bq, bt, bk, bv, qp, tp, kp, vp, woT);
  hipLaunchKernelGGL(attn_kernel, dim3(32, 48), dim3(512), 0, stream,
                     qp, tp, kp, vp, xs);
  hipLaunchKernelGGL(gemm_out_kernel, dim3(4, 48), dim3(256), 0, stream,
                     xs, woT, bo, out);
}

// Round 6
// 34.744 us; speedup vs baseline: 2.3177x; 1.0506x over previous
//
#include <hip/hip_runtime.h>
#include <hip/hip_bf16.h>

// n=48, m=32, d_model=512, H=8, DK=64, d_query=256, d_time=64
typedef __bf16 bf16x8 __attribute__((ext_vector_type(8)));
typedef float f32x4 __attribute__((ext_vector_type(4)));
typedef float f32x2 __attribute__((ext_vector_type(2)));

#if __has_builtin(__builtin_amdgcn_exp2f)
#define EXP2F __builtin_amdgcn_exp2f
#else
#define EXP2F exp2f
#endif

__device__ __forceinline__ float fastrcp(float x) {
#if __has_builtin(__builtin_amdgcn_rcpf)
  return __builtin_amdgcn_rcpf(x);
#else
  return 1.0f / x;
#endif
}

__device__ __forceinline__ f32x2 exp2_pk(f32x2 t) {
  return (f32x2){EXP2F(t[0]), EXP2F(t[1])};
}

// ---------------------------------------------------------------------------
// proj body, templated on K so the chunk loop fully unrolls and all global
// loads pipeline. B-fragments are built DIRECTLY from global W (no LDS
// staging): lane l, tile nb reads W[cbase+(l>>4)*8+j][n0+(l&15)+16*nb],
// j=0..7 — each W element read exactly once per block, 4x64B segments/inst.
// 4 waves K-split (32-k chunks, stride 4), LDS reduction at the end.
// ---------------------------------------------------------------------------
template <int K>
__device__ __forceinline__ void proj_body(
    const float* __restrict__ src, const float* __restrict__ W,
    const float* __restrict__ bias, float* __restrict__ dst,
    int bb, int t, char* smem)
{
  f32x4 (*red)[4][64] = (f32x4(*)[4][64])smem;   // [wave][nb][lane] 16 KB
  int mt = bb >> 3, nt = bb & 7;
  int m0 = mt << 4, n0 = nt << 6;
  int w = t >> 6;
  int l = t & 63, lhi = l >> 4, llo = l & 15;

  f32x4 acc[4];
  #pragma unroll
  for (int nb = 0; nb < 4; ++nb) acc[nb] = (f32x4){0.f, 0.f, 0.f, 0.f};

  constexpr int nkc = K >> 5;
  #pragma unroll
  for (int ci = 0; ci < nkc; ci += 4) {
    if (ci + 0 * 4 >= nkc) break;   // keeps t-proj (nkc=2) waves 2,3 legal
    int cw = ci + w;
    if (cw < nkc) {
      int cbase = cw << 5;
      // ---- A fragment (split f32 input in-register)
      const float* pa = src + (m0 + llo) * K + cbase + (lhi << 3);
      f32x4 f0 = *(const f32x4*)pa;
      f32x4 f1 = *(const f32x4*)(pa + 4);
      // ---- all 32 W loads issued before any conversion/MFMA
      const float* pw = W + (cbase + (lhi << 3)) * 512 + n0 + llo;
      float wf[4][8];
      #pragma unroll
      for (int nb = 0; nb < 4; ++nb)
        #pragma unroll
        for (int j = 0; j < 8; ++j)
          wf[nb][j] = pw[j * 512 + (nb << 4)];

      bf16x8 ahi, alo;
      #pragma unroll
      for (int j = 0; j < 4; ++j) {
        __bf16 h0 = (__bf16)f0[j]; ahi[j]     = h0; alo[j]     = (__bf16)(f0[j] - (float)h0);
        __bf16 h1 = (__bf16)f1[j]; ahi[4 + j] = h1; alo[4 + j] = (__bf16)(f1[j] - (float)h1);
      }
      #pragma unroll
      for (int nb = 0; nb < 4; ++nb) {
        bf16x8 bhi, blo;
        #pragma unroll
        for (int j = 0; j < 8; ++j) {
          float f = wf[nb][j];
          __bf16 h = (__bf16)f;
          bhi[j] = h;
          blo[j] = (__bf16)(f - (float)h);
        }
        acc[nb] = __builtin_amdgcn_mfma_f32_16x16x32_bf16(ahi, bhi, acc[nb], 0, 0, 0);
        acc[nb] = __builtin_amdgcn_mfma_f32_16x16x32_bf16(alo, blo, acc[nb], 0, 0, 0);
      }
    }
  }

  #pragma unroll
  for (int nb = 0; nb < 4; ++nb) red[w][nb][l] = acc[nb];
  __syncthreads();

  f32x4 s = red[0][w][l] + red[1][w][l] + red[2][w][l] + red[3][w][l];
  int col = n0 + (w << 4) + llo;
  float bias_v = bias[col];
  #pragma unroll
  for (int r = 0; r < 4; ++r)
    dst[(m0 + (lhi << 2) + r) * 512 + col] = s[r] + bias_v;
}

// ---------------------------------------------------------------------------
// Kernel 1: fused projections + Wo transpose/split.
// 144 blocks x 256 thr:
//   b [0,24):  q-proj (M=48, K=256)   [24,48): t-proj (K=64)
//   b [48,64): k-proj (M=32, K=512)   [64,80): v-proj (K=512)
//   b [80,144): Wo split -> woT[512][1024] (hi|lo)
// ---------------------------------------------------------------------------
__global__ __launch_bounds__(256) void proj_wsplit_kernel(
    const float* __restrict__ query, const float* __restrict__ time_,
    const float* __restrict__ key, const float* __restrict__ value,
    const float* __restrict__ Wq, const float* __restrict__ Wt,
    const float* __restrict__ Wk, const float* __restrict__ Wv,
    const float* __restrict__ Wo,
    const float* __restrict__ bq, const float* __restrict__ bt,
    const float* __restrict__ bk, const float* __restrict__ bv,
    float* __restrict__ qp, float* __restrict__ tp,
    float* __restrict__ kp, float* __restrict__ vp,
    __bf16* __restrict__ woT)
{
  __shared__ char smem[16896];  // max(red 16384, tile 64x65x4=16640)
  int b = blockIdx.x, t = threadIdx.x;

  if (b >= 80) {
    // ---- Wo transpose + split (f32 -> bf16 hi|lo) -> woT[512][1024]
    float (*tile)[65] = (float(*)[65])smem;
    int tb = b - 80;
    int kt = tb >> 3, nt = tb & 7;
    int k0 = kt << 6, n0 = nt << 6;
    #pragma unroll
    for (int e = 0; e < 16; ++e) {
      int idx = t + (e << 8);
      int r = idx >> 6, c = idx & 63;
      tile[r][c] = Wo[(k0 + r) * 512 + n0 + c];
    }
    __syncthreads();
    #pragma unroll
    for (int e = 0; e < 16; ++e) {
      int idx = t + (e << 8);
      int nn = idx >> 6, kk = idx & 63;
      float f = tile[kk][nn];
      __bf16 hi = (__bf16)f;
      __bf16 lo = (__bf16)(f - (float)hi);
      woT[(n0 + nn) * 1024 + k0 + kk]       = hi;
      woT[(n0 + nn) * 1024 + 512 + k0 + kk] = lo;
    }
    return;
  }

  if (b < 24)      proj_body<256>(query, Wq, bq, qp, b,      t, smem);
  else if (b < 48) proj_body<64> (time_, Wt, bt, tp, b - 24, t, smem);
  else if (b < 64) proj_body<512>(key,   Wk, bk, kp, b - 48, t, smem);
  else             proj_body<512>(value, Wv, bv, vp, b - 64, t, smem);
}

// ---------------------------------------------------------------------------
// Kernel 2: fused two-stage feature-axis attention.
// Packed-f32 inner loops, exp2-direct, no max-sub, wave-local cvl (no barrier).
// Grid (m=32, n=48), 512 thr (wave per head, lane = feature d).
// Writes x as plain bf16 rows xs[1536][512].
// ---------------------------------------------------------------------------
__global__ __launch_bounds__(512) void attn_kernel(
    const float* __restrict__ qp, const float* __restrict__ tp,
    const float* __restrict__ kp, const float* __restrict__ vp,
    __bf16* __restrict__ xs)
{
  __shared__ float cvl[8][64];
  int m = blockIdx.x, n = blockIdx.y;
  int lane = threadIdx.x & 63;
  int hs = __builtin_amdgcn_readfirstlane((int)threadIdx.x) >> 6;

  const float* kk = kp + m * 512 + hs * 64;
  const float* vv = vp + m * 512 + hs * 64;
  const float C = 0.18033688011112042f;  // 0.125 * log2(e)
  float a2 = qp[n * 512 + hs * 64 + lane] * C;
  float b2 = tp[n * 512 + hs * 64 + lane] * C;

  f32x2 a2p = {a2, a2};
  f32x2 den = {0.f, 0.f}, sv = {0.f, 0.f};
  #pragma unroll
  for (int j4 = 0; j4 < 16; ++j4) {
    f32x4 kq = *(const f32x4*)(kk + (j4 << 2));
    f32x4 vq = *(const f32x4*)(vv + (j4 << 2));
    f32x2 klo = {kq[0], kq[1]}, khi = {kq[2], kq[3]};
    f32x2 vlo = {vq[0], vq[1]}, vhi = {vq[2], vq[3]};
    f32x2 e0 = exp2_pk(a2p * klo);
    f32x2 e1 = exp2_pk(a2p * khi);
    den += e0 + e1;
    sv += e0 * vlo;
    sv += e1 * vhi;
  }
  float cv = (sv[0] + sv[1]) * fastrcp(den[0] + den[1]);
  cvl[hs][lane] = cv;   // wave-local: lgkmcnt wait suffices, no barrier

  f32x2 b2p = {b2, b2};
  f32x2 den2 = {0.f, 0.f}, sv2 = {0.f, 0.f};
  #pragma unroll
  for (int j4 = 0; j4 < 16; ++j4) {
    f32x4 c = *(const f32x4*)&cvl[hs][j4 << 2];
    f32x2 clo = {c[0], c[1]}, chi = {c[2], c[3]};
    f32x2 e0 = exp2_pk(b2p * clo);
    f32x2 e1 = exp2_pk(b2p * chi);
    den2 += e0 + e1;
    sv2 += e0 * clo;
    sv2 += e1 * chi;
  }
  float o = (sv2[0] + sv2[1]) * fastrcp(den2[0] + den2[1]);

  xs[(n * 32 + m) * 512 + hs * 64 + lane] = (__bf16)o;
}

// ---------------------------------------------------------------------------
// Kernel 3: out = x @ Wo + bo; x plain bf16 (K=512), Wo split (hi+lo share
// the A fragment). Grid (4,48) x 256: block 32m x 128n, wave w owns the
// 32x32 tile at n = bx*128 + w*32.
// ---------------------------------------------------------------------------
__global__ __launch_bounds__(256) void gemm_out_kernel(
    const __bf16* __restrict__ xs, const __bf16* __restrict__ woT,
    const float* __restrict__ bo, float* __restrict__ out)
{
  int w = threadIdx.x >> 6;
  int n0 = (blockIdx.x << 7) + (w << 5);
  int m0 = blockIdx.y << 5;
  int l = threadIdx.x & 63;
  int lhi = l >> 4, llo = l & 15;

  f32x4 acc00 = {0.f, 0.f, 0.f, 0.f};
  f32x4 acc01 = {0.f, 0.f, 0.f, 0.f};
  f32x4 acc10 = {0.f, 0.f, 0.f, 0.f};
  f32x4 acc11 = {0.f, 0.f, 0.f, 0.f};

  const __bf16* pa0  = xs  + (m0 + llo) * 512 + (lhi << 3);
  const __bf16* pa1  = pa0 + 16 * 512;
  const __bf16* pbh0 = woT + (n0 + llo) * 1024 + (lhi << 3);
  const __bf16* pbh1 = pbh0 + 16 * 1024;

  #pragma unroll 4
  for (int kc = 0; kc < 512; kc += 32) {
    bf16x8 a0  = *(const bf16x8*)(pa0 + kc);
    bf16x8 a1  = *(const bf16x8*)(pa1 + kc);
    bf16x8 bh0 = *(const bf16x8*)(pbh0 + kc);
    bf16x8 bl0 = *(const bf16x8*)(pbh0 + 512 + kc);
    bf16x8 bh1 = *(const bf16x8*)(pbh1 + kc);
    bf16x8 bl1 = *(const bf16x8*)(pbh1 + 512 + kc);
    acc00 = __builtin_amdgcn_mfma_f32_16x16x32_bf16(a0, bh0, acc00, 0, 0, 0);
    acc01 = __builtin_amdgcn_mfma_f32_16x16x32_bf16(a0, bh1, acc01, 0, 0, 0);
    acc10 = __builtin_amdgcn_mfma_f32_16x16x32_bf16(a1, bh0, acc10, 0, 0, 0);
    acc11 = __builtin_amdgcn_mfma_f32_16x16x32_bf16(a1, bh1, acc11, 0, 0, 0);
    acc00 = __builtin_amdgcn_mfma_f32_16x16x32_bf16(a0, bl0, acc00, 0, 0, 0);
    acc01 = __builtin_amdgcn_mfma_f32_16x16x32_bf16(a0, bl1, acc01, 0, 0, 0);
    acc10 = __builtin_amdgcn_mfma_f32_16x16x32_bf16(a1, bl0, acc10, 0, 0, 0);
    acc11 = __builtin_amdgcn_mfma_f32_16x16x32_bf16(a1, bl1, acc11, 0, 0, 0);
  }

  int colA = n0 + llo, colB = colA + 16;
  float boA = bo[colA], boB = bo[colB];
  #pragma unroll
  for (int r = 0; r < 4; ++r) {
    int rowA = m0 + (lhi << 2) + r;
    int rowB = rowA + 16;
    out[rowA * 512 + colA] = acc00[r] + boA;
    out[rowA * 512 + colB] = acc01[r] + boB;
    out[rowB * 512 + colA] = acc10[r] + boA;
    out[rowB * 512 + colB] = acc11[r] + boB;
  }
}

// ---------------------------------------------------------------------------
extern "C" void kernel_launch(void* const* d_in, const int* in_sizes, int n_in,
                              void* d_out, int out_size, void* d_ws, size_t ws_size,
                              hipStream_t stream) {
  const float* query = (const float*)d_in[0];
  const float* key   = (const float*)d_in[1];
  const float* value = (const float*)d_in[2];
  const float* time_ = (const float*)d_in[3];
  const float* Wq = (const float*)d_in[4];
  const float* bq = (const float*)d_in[5];
  const float* Wt = (const float*)d_in[6];
  const float* bt = (const float*)d_in[7];
  const float* Wk = (const float*)d_in[8];
  const float* bk = (const float*)d_in[9];
  const float* Wv = (const float*)d_in[10];
  const float* bv = (const float*)d_in[11];
  const float* Wo = (const float*)d_in[12];
  const float* bo = (const float*)d_in[13];

  // ws layout (byte offsets, 16B-aligned):
  char* wsb = (char*)d_ws;
  float*  qp  = (float*) (wsb + 0);        // 48*512 f32
  float*  tp  = (float*) (wsb + 98304);    // 48*512 f32
  float*  kp  = (float*) (wsb + 196608);   // 32*512 f32
  float*  vp  = (float*) (wsb + 262144);   // 32*512 f32
  __bf16* xs  = (__bf16*)(wsb + 327680);   // 1536*512 bf16
  __bf16* woT = (__bf16*)(wsb + 1900544);  // 512*1024 bf16 (end 2949120 B)
  float* out = (float*)d_out;

  hipLaunchKernelGGL(proj_wsplit_kernel, dim3(144), dim3(256), 0, stream,
                     query, time_, key, value, Wq, Wt, Wk, Wv, Wo,
                     bq, bt, bk, bv, qp, tp, kp, vp, woT);
  hipLaunchKernelGGL(attn_kernel, dim3(32, 48), dim3(512), 0, stream,
                     qp, tp, kp, vp, xs);
  hipLaunchKernelGGL(gemm_out_kernel, dim3(4, 48), dim3(256), 0, stream,
                     xs, woT, bo, out);
}